// Round 11
// baseline (421.655 us; speedup 1.0000x reference)
//
#include <hip/hip_runtime.h>
#include <stdint.h>

#define EDIM 2048
#define HH 16
#define DD 128
#define SS 2048
#define BB 2
#define NT2 32   // K / 64 K-tiles for the 256^2 GEMM

typedef __attribute__((ext_vector_type(8))) __bf16 bf16x8;
typedef __attribute__((ext_vector_type(8))) unsigned short ushort8;
typedef __attribute__((ext_vector_type(4))) unsigned short ushort4v;
typedef __attribute__((ext_vector_type(4))) float f32x4;

#define MFMA16 __builtin_amdgcn_mfma_f32_16x16x32_bf16

__device__ __forceinline__ unsigned short f2b(float f) {
    union { float f; unsigned int u; } v; v.f = f;
    unsigned int u = v.u;
    unsigned int r = (u + 0x7fffu + ((u >> 16) & 1u)) >> 16;  // RNE
    return (unsigned short)r;
}
__device__ __forceinline__ float b2f(unsigned short h) {
    union { unsigned int u; float f; } v; v.u = ((unsigned int)h) << 16;
    return v.f;
}
__device__ __forceinline__ bf16x8 lds8(const unsigned short* p) {
    return __builtin_bit_cast(bf16x8, *(const ushort8*)p);
}
__device__ __forceinline__ void gl_lds16(const unsigned short* g, unsigned short* l) {
    __builtin_amdgcn_global_load_lds(
        (const __attribute__((address_space(1))) void*)(const void*)g,
        (__attribute__((address_space(3))) void*)(void*)l, 16, 0, 0);
}
__device__ __forceinline__ float fexp2(float x) {
    float r;
    asm volatile("v_exp_f32 %0, %1\n\ts_nop 1" : "=v"(r) : "v"(x));
    return r;
}
__device__ __forceinline__ void barrier_np() {
    __builtin_amdgcn_s_barrier();
    __builtin_amdgcn_sched_barrier(0);
}

// ---------------- conversion / transpose ----------------

__global__ __launch_bounds__(256) void k_cvt_x(const float4* __restrict__ x,
                                               ushort4v* __restrict__ xb) {
    size_t i = (size_t)blockIdx.x * 256 + threadIdx.x;
    float4 v = x[i];
    ushort4v o;
    o.x = f2b(v.x); o.y = f2b(v.y); o.z = f2b(v.z); o.w = f2b(v.w);
    xb[i] = o;
}

__global__ __launch_bounds__(256) void k_trans(const float* __restrict__ W0,
                                               const float* __restrict__ W1,
                                               const float* __restrict__ W2,
                                               const float* __restrict__ W3,
                                               unsigned short* __restrict__ Wt) {
    const float* W = (blockIdx.z == 0) ? W0 : (blockIdx.z == 1) ? W1
                     : (blockIdx.z == 2) ? W2 : W3;
    unsigned short* out = Wt + (size_t)blockIdx.z * EDIM * EDIM;
    __shared__ float t[64][65];
    int r0 = blockIdx.y * 64, c0 = blockIdx.x * 64;
#pragma unroll
    for (int i = 0; i < 16; ++i) {
        int e = threadIdx.x + i * 256; int r = e >> 6, c = e & 63;
        t[r][c] = W[(size_t)(r0 + r) * EDIM + c0 + c];
    }
    __syncthreads();
#pragma unroll
    for (int i = 0; i < 16; ++i) {
        int e = threadIdx.x + i * 256; int r = e >> 6, c = e & 63;
        out[(size_t)(c0 + r) * EDIM + r0 + c] = f2b(t[c][r]);  // Wt[n][k] = W[k][n]
    }
}

// ======== 256^2 8-phase-style GEMM (T1+T2+T3+T4+T5) for QKV ========
// LDS layout per (buf,half): [128 rows][64 k] bf16, row stride 128 B.
// Swizzle: byte ^= ((row&7)<<4)  (3-bit — 8 rows span all 32 banks; 2 lanes/bank
// free per m136). Involution: f reads bits 7-9, XORs bits 4-6 -> f(x^f(x))=f(x),
// so inverse-applying f to the GLOBAL SOURCE of the linear DMA (rule 21) is exact.

__device__ __forceinline__ void stage16(const unsigned short* __restrict__ G,
                                        unsigned short* L, int wave, int lane, int s) {
    // LDS linear chunk this lane's 16B lands at: q = (s*8+wave)*1024 + lane*16
    int q  = (s * 8 + wave) * 1024 + lane * 16;
    int qp = q ^ (((q >> 7) & 7) << 4);          // fetch data the READ expects here
    int row = qp >> 7, col = (qp & 127) >> 1;
    gl_lds16(G + (size_t)row * EDIM + col, L + (s * 8 + wave) * 512);
}
__device__ __forceinline__ bf16x8 frag_read(const unsigned short* Lhalf,
                                            int rowl, int kk, int lg) {
    int b = rowl * 128 + kk * 64 + lg * 16;
    b ^= ((b >> 7) & 7) << 4;
    return lds8(Lhalf + (b >> 1));
}

#define QKV_PHASE(MF0) do {                                                    \
    bf16x8 a00 = frag_read(Ah, (MF0) * 16 + lr, 0, lg);                        \
    bf16x8 a01 = frag_read(Ah, (MF0) * 16 + lr, 1, lg);                        \
    bf16x8 a10 = frag_read(Ah, (MF0) * 16 + 16 + lr, 0, lg);                   \
    bf16x8 a11 = frag_read(Ah, (MF0) * 16 + 16 + lr, 1, lg);                   \
    __builtin_amdgcn_s_setprio(1);                                             \
    _Pragma("unroll")                                                          \
    for (int nf = 0; nf < 4; ++nf) {                                           \
        acc[(MF0)][nf]     = MFMA16(a00, bfr[nf][0], acc[(MF0)][nf], 0, 0, 0); \
        acc[(MF0)][nf]     = MFMA16(a01, bfr[nf][1], acc[(MF0)][nf], 0, 0, 0); \
        acc[(MF0) + 1][nf] = MFMA16(a10, bfr[nf][0], acc[(MF0) + 1][nf], 0, 0, 0); \
        acc[(MF0) + 1][nf] = MFMA16(a11, bfr[nf][1], acc[(MF0) + 1][nf], 0, 0, 0); \
    }                                                                          \
    __builtin_amdgcn_s_setprio(0);                                             \
} while (0)

__global__ __launch_bounds__(512) void k_gemm_qkv2(const unsigned short* __restrict__ xb,
                                                   const unsigned short* __restrict__ Wt,
                                                   unsigned short* __restrict__ Qd,
                                                   unsigned short* __restrict__ Kd,
                                                   unsigned short* __restrict__ Vtd) {
    __shared__ alignas(16) unsigned short As[2][2][8192];   // [buf][half][128*64]
    __shared__ alignas(16) unsigned short Bs[2][2][8192];
    const int tid = threadIdx.x, wave = tid >> 6, lane = tid & 63;
    const int lr = lane & 15, lg = lane >> 4;
    const int wm = wave >> 2, wn = wave & 3;
    // XCD-chunked bijective remap: 384 blocks = 8 XCD x 48 (3 n-panels x 16 m)
    const int nb   = (blockIdx.x & 7) * 48 + (blockIdx.x >> 3);
    const int wsel = nb >> 7, rr = nb & 127;
    const size_t m0 = (size_t)(rr & 15) * 256;
    const size_t n0 = (size_t)(rr >> 4) * 256;
    const unsigned short* A  = xb;
    const unsigned short* Bw = Wt + (size_t)wsel * EDIM * EDIM;

    f32x4 acc[8][4] = {};

    // prologue: queue order B(0)x4, A(0)x4, B(1)x4
#pragma unroll
    for (int h = 0; h < 2; ++h)
#pragma unroll
        for (int s = 0; s < 2; ++s)
            stage16(Bw + (n0 + h * 128) * EDIM, Bs[0][h], wave, lane, s);
#pragma unroll
    for (int h = 0; h < 2; ++h)
#pragma unroll
        for (int s = 0; s < 2; ++s)
            stage16(A + (m0 + h * 128) * EDIM, As[0][h], wave, lane, s);
#pragma unroll
    for (int h = 0; h < 2; ++h)
#pragma unroll
        for (int s = 0; s < 2; ++s)
            stage16(Bw + (n0 + h * 128) * EDIM + 64, Bs[1][h], wave, lane, s);
    asm volatile("s_waitcnt vmcnt(4)" ::: "memory");   // B(0),A(0) landed; B(1) in flight
    __builtin_amdgcn_sched_barrier(0);
    barrier_np();

    for (int u = 0; u < NT2; ++u) {
        const int cur = u & 1;
        const unsigned short* Ah = As[cur][wm];
        // ---- phase 0: B-frags (8 reads) + A mf{0,1} (4 reads), 16 MFMA ----
        bf16x8 bfr[4][2];
#pragma unroll
        for (int nf = 0; nf < 4; ++nf) {
            int nl = wn * 64 + nf * 16 + lr;
            const unsigned short* Bh = Bs[cur][nl >> 7];
#pragma unroll
            for (int kk = 0; kk < 2; ++kk)
                bfr[nf][kk] = frag_read(Bh, nl & 127, kk, lg);
        }
        QKV_PHASE(0);
        barrier_np();
        // ---- phase 1: stage A(u+1) -> other buf (its tile-(u-1) reads closed) ----
        if (u + 1 < NT2) {
#pragma unroll
            for (int h = 0; h < 2; ++h)
#pragma unroll
                for (int s = 0; s < 2; ++s)
                    stage16(A + (m0 + h * 128) * EDIM + (u + 1) * 64,
                            As[(u + 1) & 1][h], wave, lane, s);
        }
        QKV_PHASE(2);
        barrier_np();
        // ---- phase 2: stage B(u+2) -> cur buf B region (read-closed at phase 0) ----
        if (u + 2 < NT2) {
#pragma unroll
            for (int h = 0; h < 2; ++h)
#pragma unroll
                for (int s = 0; s < 2; ++s)
                    stage16(Bw + (n0 + h * 128) * EDIM + (u + 2) * 64,
                            Bs[cur][h], wave, lane, s);
        }
        QKV_PHASE(4);
        barrier_np();
        // ---- phase 3: last A quadrant; counted vmcnt (never 0 mid-loop) ----
        QKV_PHASE(6);
        if (u + 2 < NT2) asm volatile("s_waitcnt vmcnt(4)" ::: "memory"); // A(u+1),B(u+1) done
        else             asm volatile("s_waitcnt vmcnt(0)" ::: "memory"); // tail drain
        __builtin_amdgcn_sched_barrier(0);
        barrier_np();
    }

    // ---- epilogue ----
    if (wsel < 2) {
        unsigned short* dst = wsel ? Kd : Qd;
#pragma unroll
        for (int mf = 0; mf < 8; ++mf)
#pragma unroll
            for (int nf = 0; nf < 4; ++nf)
#pragma unroll
                for (int r = 0; r < 4; ++r) {
                    int row = (int)m0 + wm * 128 + mf * 16 + lg * 4 + r;   // token
                    int e   = (int)n0 + wn * 64 + nf * 16 + lr;            // embed col
                    int b = row >> 11, s = row & (SS - 1);
                    int h = e >> 7,  d = e & (DD - 1);
                    dst[(((size_t)(b * HH + h)) * SS + s) * DD + d] = f2b(acc[mf][nf][r]);
                }
    } else {
#pragma unroll
        for (int mf = 0; mf < 8; ++mf)
#pragma unroll
            for (int nf = 0; nf < 4; ++nf) {
                int row0 = (int)m0 + wm * 128 + mf * 16 + lg * 4;
                int e    = (int)n0 + wn * 64 + nf * 16 + lr;
                int b = row0 >> 11, s0 = row0 & (SS - 1);
                int h = e >> 7, d = e & (DD - 1);
                ushort4v pk;
                pk.x = f2b(acc[mf][nf][0]); pk.y = f2b(acc[mf][nf][1]);
                pk.z = f2b(acc[mf][nf][2]); pk.w = f2b(acc[mf][nf][3]);
                *(ushort4v*)(Vtd + (((size_t)(b * HH + h)) * DD + d) * SS + s0) = pk;
            }
    }
}

// ---------------- GEMM core (m97 structure: 128^2 tile, BK=32, 4 waves) ----------------

__device__ __forceinline__ void gemm_core(const unsigned short* __restrict__ A,
                                          const unsigned short* __restrict__ Bt,
                                          int K, size_t m0, size_t n0,
                                          unsigned short* As, unsigned short* Bs,
                                          f32x4 acc[4][4], int wave, int lane) {
    const int wm = wave >> 1, wn = wave & 1;
    const int lg = lane >> 4, lr = lane & 15;
    for (int kt = 0; kt < K; kt += 32) {
#pragma unroll
        for (int j = 0; j < 2; ++j) {
            const int cb = j * 256 + wave * 64;   // wave-uniform LDS chunk base
            const int c  = cb + lane;             // per-lane 16B chunk id
            gl_lds16(A  + (m0 + (size_t)(c >> 2)) * K + kt + (c & 3) * 8, As + cb * 8);
            gl_lds16(Bt + (n0 + (size_t)(c >> 2)) * K + kt + (c & 3) * 8, Bs + cb * 8);
        }
        __syncthreads();
        bf16x8 af[4], bg[4];
#pragma unroll
        for (int i = 0; i < 4; ++i) {
            af[i] = lds8(As + (wm * 64 + i * 16 + lr) * 32 + lg * 8);
            bg[i] = lds8(Bs + (wn * 64 + i * 16 + lr) * 32 + lg * 8);
        }
#pragma unroll
        for (int i = 0; i < 4; ++i)
#pragma unroll
            for (int j = 0; j < 4; ++j)
                acc[i][j] = MFMA16(af[i], bg[j], acc[i][j], 0, 0, 0);
        __syncthreads();
    }
}

// out-proj GEMM: m97 core + T1 XCD-chunk remap (512 = 8 XCD x 64 = 2 n x 32 m)
__global__ __launch_bounds__(256) void k_gemm_out(const unsigned short* __restrict__ Ob,
                                                  const unsigned short* __restrict__ Wto,
                                                  float* __restrict__ y) {
    __shared__ alignas(16) unsigned short As[128 * 32];
    __shared__ alignas(16) unsigned short Bs[128 * 32];
    const int tid = threadIdx.x, wave = tid >> 6, lane = tid & 63;
    const int nb = (blockIdx.x & 7) * 64 + (blockIdx.x >> 3);
    const size_t m0 = (size_t)(nb & 31) * 128;
    const size_t n0 = (size_t)(nb >> 5) * 128;
    f32x4 acc[4][4] = {};
    gemm_core(Ob, Wto, EDIM, m0, n0, As, Bs, acc, wave, lane);
    const int wm = wave >> 1, wn = wave & 1, lg = lane >> 4, lr = lane & 15;
#pragma unroll
    for (int i = 0; i < 4; ++i)
#pragma unroll
        for (int j = 0; j < 4; ++j)
#pragma unroll
            for (int r = 0; r < 4; ++r) {
                size_t row = m0 + wm * 64 + i * 16 + lg * 4 + r;
                size_t col = n0 + wn * 64 + j * 16 + lr;
                y[row * EDIM + col] = acc[i][j][r];
            }
}

// ---------------- RoPE (1/sqrt(D) AND log2(e) folded into Q scale) ----------------

__global__ __launch_bounds__(256) void k_rope(unsigned short* __restrict__ Q,
                                              unsigned short* __restrict__ K) {
    int idx = blockIdx.x * 256 + threadIdx.x;   // 2*16*2048*64
    int i  = idx & 63;
    int s  = (idx >> 6) & (SS - 1);
    int bh = idx >> 17;
    size_t base = ((size_t)bh * SS + s) * DD;
    float inv = __expf(-0.14391156608f * (float)i);  // 10000^(-i/64)
    float ang = (float)s * inv;
    float sn, cs; sincosf(ang, &sn, &cs);
    const float qs = 0.08838834764831845f * 1.44269504088896340736f;  // 1/sqrt(128)*log2e
    float q1 = b2f(Q[base + i]), q2 = b2f(Q[base + 64 + i]);
    float k1 = b2f(K[base + i]), k2 = b2f(K[base + 64 + i]);
    Q[base + i]      = f2b((q1 * cs - q2 * sn) * qs);
    Q[base + 64 + i] = f2b((q2 * cs + q1 * sn) * qs);
    K[base + i]      = f2b(k1 * cs - k2 * sn);
    K[base + 64 + i] = f2b(k2 * cs + k1 * sn);
}

// ---------------- flash attention (causal), paired q-tiles, no-max softmax ----------------

__device__ __forceinline__ void attn_tile(const unsigned short* Ks, const unsigned short* Vs,
                                          unsigned short* Ps, const bf16x8 qf[4],
                                          f32x4 o[9], bool maskdiag,
                                          int wave, int lg, int lr) {
    f32x4 sa[4] = {};
    __builtin_amdgcn_s_setprio(1);
#pragma unroll
    for (int nf = 0; nf < 4; ++nf)
#pragma unroll
        for (int kk = 0; kk < 4; ++kk) {
            bf16x8 kb = lds8(Ks + (nf * 16 + lr) * 136 + kk * 32 + lg * 8);
            sa[nf] = MFMA16(qf[kk], kb, sa[nf], 0, 0, 0);
        }
    __builtin_amdgcn_s_setprio(0);
    if (maskdiag) {
#pragma unroll
        for (int nf = 0; nf < 4; ++nf)
#pragma unroll
            for (int r = 0; r < 4; ++r) {
                int col = nf * 16 + lr, rw = wave * 16 + lg * 4 + r;
                if (col > rw) sa[nf][r] = -__builtin_inff();
            }
    }
#pragma unroll
    for (int nf = 0; nf < 4; ++nf)
#pragma unroll
        for (int r = 0; r < 4; ++r) {
            float p = fexp2(sa[nf][r]);
            unsigned int u = __builtin_bit_cast(unsigned int, p);
            Ps[(wave * 16 + lg * 4 + r) * 72 + nf * 16 + lr] =
                (unsigned short)((u + 0x8000u) >> 16);
        }
    bf16x8 pa0 = lds8(Ps + (wave * 16 + lr) * 72 + lg * 8);
    bf16x8 pa1 = lds8(Ps + (wave * 16 + lr) * 72 + 32 + lg * 8);
    __builtin_amdgcn_s_setprio(1);
#pragma unroll
    for (int nf = 0; nf < 9; ++nf) {   // nf==8: ones rows -> o[8] = denominator
        bf16x8 v0 = lds8(Vs + (nf * 16 + lr) * 72 + lg * 8);
        bf16x8 v1 = lds8(Vs + (nf * 16 + lr) * 72 + 32 + lg * 8);
        o[nf] = MFMA16(pa0, v0, o[nf], 0, 0, 0);
        o[nf] = MFMA16(pa1, v1, o[nf], 0, 0, 0);
    }
    __builtin_amdgcn_s_setprio(0);
}

__global__ __launch_bounds__(256) void k_attn(const unsigned short* __restrict__ Q,
                                              const unsigned short* __restrict__ Kg,
                                              const unsigned short* __restrict__ Vt,
                                              unsigned short* __restrict__ Ob) {
    __shared__ alignas(16) unsigned short Ks[64 * 136];
    __shared__ alignas(16) unsigned short Vs[144 * 72];
    __shared__ alignas(16) unsigned short Ps[64 * 72];
    const int tid = threadIdx.x, wave = tid >> 6, lane = tid & 63;
    const int lg = lane >> 4, lr = lane & 15;
    const int bh = blockIdx.y;
    const int tp = blockIdx.x;
    const int qa0 = tp * 64, qb0 = (31 - tp) * 64;
    const int nta = tp + 1, ntb = 32 - tp;
    const size_t qkb = (size_t)bh * SS * DD;
    const size_t vbb = (size_t)bh * DD * SS;
    {
        ushort4v one4; one4.x = 0x3F80; one4.y = 0x3F80; one4.z = 0x3F80; one4.w = 0x3F80;
        *(ushort4v*)(Vs + (128 + (tid >> 4)) * 72 + (tid & 15) * 4) = one4;
    }
    bf16x8 qfA[4], qfB[4];
    {
        const unsigned short* qpA = Q + qkb + (size_t)(qa0 + wave * 16 + lr) * DD + lg * 8;
        const unsigned short* qpB = Q + qkb + (size_t)(qb0 + wave * 16 + lr) * DD + lg * 8;
#pragma unroll
        for (int kk = 0; kk < 4; ++kk) {
            qfA[kk] = __builtin_bit_cast(bf16x8, *(const ushort8*)(qpA + kk * 32));
            qfB[kk] = __builtin_bit_cast(bf16x8, *(const ushort8*)(qpB + kk * 32));
        }
    }
    f32x4 oA[9] = {}, oB[9] = {};
    ushort8 kr[4], vr[4];
#pragma unroll
    for (int i = 0; i < 4; ++i) {
        int c = tid + i * 256;
        kr[i] = *(const ushort8*)(Kg + qkb + (size_t)(c >> 4) * DD + (c & 15) * 8);
        vr[i] = *(const ushort8*)(Vt + vbb + (size_t)(c >> 3) * SS + (c & 7) * 8);
    }
    for (int t = 0; t < ntb; ++t) {
        __syncthreads();
#pragma unroll
        for (int i = 0; i < 4; ++i) {
            int c = tid + i * 256;
            *(ushort8*)(Ks + (c >> 4) * 136 + (c & 15) * 8) = kr[i];
            *(ushort8*)(Vs + (c >> 3) * 72 + (c & 7) * 8) = vr[i];
        }
        __syncthreads();
        if (t + 1 < ntb) {
            int kv0 = (t + 1) * 64;
#pragma unroll
            for (int i = 0; i < 4; ++i) {
                int c = tid + i * 256;
                kr[i] = *(const ushort8*)(Kg + qkb + (size_t)(kv0 + (c >> 4)) * DD + (c & 15) * 8);
                vr[i] = *(const ushort8*)(Vt + vbb + (size_t)(c >> 3) * SS + kv0 + (c & 7) * 8);
            }
        }
        attn_tile(Ks, Vs, Ps, qfB, oB, t == ntb - 1, wave, lg, lr);
        if (t < nta)
            attn_tile(Ks, Vs, Ps, qfA, oA, t == nta - 1, wave, lg, lr);
    }
    const int b = bh >> 4, h = bh & 15;
#pragma unroll
    for (int nf = 0; nf < 8; ++nf)
#pragma unroll
        for (int r = 0; r < 4; ++r) {
            int sA = qa0 + wave * 16 + lg * 4 + r;
            int sB = qb0 + wave * 16 + lg * 4 + r;
            int e = h * DD + nf * 16 + lr;
            Ob[((size_t)b * SS + sA) * EDIM + e] = f2b(oA[nf][r] / oA[8][r]);
            Ob[((size_t)b * SS + sB) * EDIM + e] = f2b(oB[nf][r] / oB[8][r]);
        }
}

// ---------------- launch ----------------

extern "C" void kernel_launch(void* const* d_in, const int* in_sizes, int n_in,
                              void* d_out, int out_size, void* d_ws, size_t ws_size,
                              hipStream_t stream) {
    const float* x  = (const float*)d_in[0];
    const float* Wq = (const float*)d_in[1];
    const float* Wk = (const float*)d_in[2];
    const float* Wv = (const float*)d_in[3];
    const float* Wo = (const float*)d_in[4];
    float* y = (float*)d_out;
    char* ws = (char*)d_ws;
    unsigned short* xb  = (unsigned short*)(ws);
    unsigned short* Wt  = (unsigned short*)(ws + (size_t)16777216);
    unsigned short* Qd  = (unsigned short*)(ws + (size_t)50331648);
    unsigned short* Kd  = (unsigned short*)(ws + (size_t)67108864);
    unsigned short* Vtd = (unsigned short*)(ws + (size_t)83886080);
    unsigned short* Ob  = (unsigned short*)(ws + (size_t)100663296);

    hipLaunchKernelGGL(k_cvt_x, dim3(8192), dim3(256), 0, stream, (const float4*)x, (ushort4v*)xb);
    hipLaunchKernelGGL(k_trans, dim3(32, 32, 4), dim3(256), 0, stream, Wq, Wk, Wv, Wo, Wt);
    hipLaunchKernelGGL(k_gemm_qkv2, dim3(384), dim3(512), 0, stream, xb, Wt, Qd, Kd, Vtd);
    hipLaunchKernelGGL(k_rope, dim3(16384), dim3(256), 0, stream, Qd, Kd);
    hipLaunchKernelGGL(k_attn, dim3(16, 32), dim3(256), 0, stream, Qd, Kd, Vtd, Ob);
    hipLaunchKernelGGL(k_gemm_out, dim3(512), dim3(256), 0, stream,
                       Ob, Wt + (size_t)3 * EDIM * EDIM, y);
}